// Round 10
// baseline (197.221 us; speedup 1.0000x reference)
//
#include <hip/hip_runtime.h>
#include <math.h>

#define N_NODES 100000
#define N_EDGES 1600000
#define NBUK 782                  // buckets of 128 nodes (dst >> 7); 782*128 = 100096
#define BNODES 128
#define CAP 2560                  // slots per bucket (mean ~2046, ~11 sigma margin)
#define CAPB (CAP * 8)            // bucket region bytes in the u64 pkd buffer
#define NCHUNK 512                // scatter chunk blocks
#define CPE 3125                  // edges per chunk (512*3125 = 1.6M exact)
#define NTBLK 1563                // transform blocks (1563*1024 >= 1.6M node-feats)
#define WS 52                     // transposed-weight LDS stride (16B-aligned)
#define RPW (BNODES + 1)          // rowptr entries per bucket (129)

// scatter-path dynamic LDS layout (60,352 B; transform path needs 10,048)
#define SM_LCUR  0                // int[NBUK]   3128
#define SM_GBASE 3128             // int[NBUK]   3128
#define SM_SC    6256             // int[1024]   4096
#define SM_UPDL  10352            // u64[CPE]   25000 (8-aligned)
#define SM_SPDL  35352            // u64[CPE]   25000
#define SM_TOTAL 60352

#define NTL(p) __builtin_nontemporal_load(p)

// ---------------------------------------------------------------------------
__device__ __forceinline__ unsigned bf16_rne(float x) {
    unsigned u = __float_as_uint(x);
    return (u + 0x7FFFu + ((u >> 16) & 1u)) >> 16;
}

// L0-bypassing 16B gather: two device-scope (sc0) 8B loads. The Y tables are
// 6.4 MB with ~0 per-CU reuse — L0 only burns MSHRs on this path; sc0 moves
// miss tracking to the deeper vmcnt queue (the CU-level concurrency cap that
// pinned every aggregate variant at ~43 µs).
__device__ __forceinline__ uint4 ldq_sc0(const uint4* __restrict__ p) {
    const unsigned long long* q = (const unsigned long long*)p;
    unsigned long long a = __hip_atomic_load(q,     __ATOMIC_RELAXED,
                                             __HIP_MEMORY_SCOPE_AGENT);
    unsigned long long b = __hip_atomic_load(q + 1, __ATOMIC_RELAXED,
                                             __HIP_MEMORY_SCOPE_AGENT);
    uint4 r;
    r.x = (unsigned)a; r.y = (unsigned)(a >> 32);
    r.z = (unsigned)b; r.w = (unsigned)(b >> 32);
    return r;
}

// accumulate one 16B chunk (4 packed bf16 pairs) with weight uu
__device__ __forceinline__ void accq(float acc[4], uint4 w, float uu) {
    acc[0] += fmaf(uu, __uint_as_float(w.x & 0xFFFF0000u), __uint_as_float(w.x << 16));
    acc[1] += fmaf(uu, __uint_as_float(w.y & 0xFFFF0000u), __uint_as_float(w.y << 16));
    acc[2] += fmaf(uu, __uint_as_float(w.z & 0xFFFF0000u), __uint_as_float(w.z << 16));
    acc[3] += fmaf(uu, __uint_as_float(w.w & 0xFFFF0000u), __uint_as_float(w.w << 16));
}

// ---------------------------------------------------------------------------
// K1 merged (UNCHANGED from round 8's 45.7 µs version): blocks [0,NCHUNK)
// bucket-scatter via per-chunk LDS counting sort (one global atomic per
// chunk×bucket); blocks [NCHUNK,...) run the layer-1 transform.
__global__ __launch_bounds__(1024)
void fused_transform_scatter(const float* __restrict__ X,
                             const float* __restrict__ W,
                             const float* __restrict__ root,
                             const float* __restrict__ bias,
                             unsigned* __restrict__ YPH, float* __restrict__ R,
                             const int* __restrict__ src,
                             const int* __restrict__ dst,
                             const float* __restrict__ u,
                             int* __restrict__ cursor,
                             unsigned long long* __restrict__ pkd) {
    extern __shared__ char smem[];
    int t = threadIdx.x;
    if (blockIdx.x < NCHUNK) {
        int c = blockIdx.x;
        int* lcur = (int*)(smem + SM_LCUR);
        int* gbase = (int*)(smem + SM_GBASE);
        int* sc = (int*)(smem + SM_SC);
        unsigned long long* updl = (unsigned long long*)(smem + SM_UPDL);
        unsigned long long* spdl = (unsigned long long*)(smem + SM_SPDL);

        for (int i = t; i < NBUK; i += 1024) lcur[i] = 0;
        __syncthreads();
        for (int j = t; j < CPE; j += 1024) {
            int e = c * CPE + j;
            int d = NTL(dst + e);
            float uu = NTL(u + e);
            uu = uu < 0.0f ? 0.0f : (uu > 1.0f ? 1.0f : uu);
            int u15 = (int)fmaf(uu, 32767.0f, 0.5f);
            unsigned pk32 = (unsigned)NTL(src + e) | ((unsigned)u15 << 17);
            updl[j] = (unsigned long long)pk32 |
                      ((unsigned long long)(unsigned)d << 32);
            atomicAdd(&lcur[d >> 7], 1);
        }
        __syncthreads();

        int v = (t < NBUK) ? lcur[t] : 0;
        sc[t] = v;
        __syncthreads();
        for (int off = 1; off < 1024; off <<= 1) {
            int x = (t >= off) ? sc[t - off] : 0;
            __syncthreads();
            sc[t] += x;
            __syncthreads();
        }
        if (t < NBUK) {
            int ex = sc[t] - v;
            lcur[t] = ex;
            int base = t * CAP + atomicAdd(&cursor[t], v);
            gbase[t] = base - ex;
        }
        __syncthreads();

        for (int j = t; j < CPE; j += 1024) {
            unsigned long long w = updl[j];
            int b = (int)(w >> 39) & 0x3FF;
            int p = atomicAdd(&lcur[b], 1);
            spdl[p] = w;
        }
        __syncthreads();

        for (int j = t; j < CPE; j += 1024) {
            unsigned long long w = spdl[j];
            int b = (int)(w >> 39) & 0x3FF;
            int g = gbase[b] + j;
            if (g < (b + 1) * CAP)
                pkd[g] = w;
        }
    } else {
        float* sW0 = (float*)smem;
        float* sWd = (float*)(smem + 3328);
        float* sR  = (float*)(smem + 6656);
        float* sB  = (float*)(smem + 9984);
        int bid = blockIdx.x - NCHUNK;
        for (int i = t; i < 48 * 16; i += 1024) {
            int f = i >> 4, o = i & 15;
            float w0 = W[i];
            float w1 = W[48 * 16 + i];
            sW0[o * WS + f] = w0;
            sWd[o * WS + f] = w1 - w0;
            sR[o * WS + f]  = root[i];
        }
        if (t < 16) sB[t] = bias[t];
        __syncthreads();

        int idx = bid * 1024 + t;
        int n = idx >> 4;
        int o = idx & 15;
        if (n >= N_NODES) return;

        const float4* xr  = (const float4*)(X + (long)n * 48);
        const float4* w0p = (const float4*)(sW0 + o * WS);
        const float4* wdp = (const float4*)(sWd + o * WS);
        const float4* wrp = (const float4*)(sR  + o * WS);
        float a0 = 0.0f, a1 = 0.0f, ar = 0.0f;
#pragma unroll
        for (int fc = 0; fc < 12; ++fc) {
            float4 xv = xr[fc];
            float4 w0 = w0p[fc];
            float4 wd = wdp[fc];
            float4 wr = wrp[fc];
            a0 = fmaf(xv.x, w0.x, a0); a0 = fmaf(xv.y, w0.y, a0);
            a0 = fmaf(xv.z, w0.z, a0); a0 = fmaf(xv.w, w0.w, a0);
            a1 = fmaf(xv.x, wd.x, a1); a1 = fmaf(xv.y, wd.y, a1);
            a1 = fmaf(xv.z, wd.z, a1); a1 = fmaf(xv.w, wd.w, a1);
            ar = fmaf(xv.x, wr.x, ar); ar = fmaf(xv.y, wr.y, ar);
            ar = fmaf(xv.z, wr.z, ar); ar = fmaf(xv.w, wr.w, ar);
        }
        YPH[idx] = bf16_rne(a0) | (bf16_rne(a1) << 16);
        R[idx]   = ar + sB[o];
    }
}

// ---------------------------------------------------------------------------
// K3 (block = 512, one block per 128-node bucket): stage + histogram + scan +
// LDS counting sort (round-8 structure, unchanged); sorted pk persisted in
// place + rptab. Aggregation: 4-lane quad-split with sc0 (L0-bypass) gathers.
__global__ __launch_bounds__(512)
void aggregate1(const int* __restrict__ cursor,
                unsigned long long* __restrict__ pkd,
                int* __restrict__ rptab,
                const uint4* __restrict__ YPH1,
                const float* __restrict__ R1,
                const float* __restrict__ W2,
                const float* __restrict__ root2,
                const float* __restrict__ b2,
                unsigned* __restrict__ YPH2,
                float* __restrict__ R2) {
    __shared__ unsigned long long updl[CAP];   // 20480 B
    __shared__ unsigned spk[CAP];              // 10240 B
    __shared__ int rp[RPW];
    __shared__ int cur[BNODES];
    __shared__ float sW0[256], sWd[256], sR[256], sB[16];
    int t = threadIdx.x, b = blockIdx.x;

    if (t < 256) {
        float w0 = W2[t], w1 = W2[256 + t];
        sW0[t] = w0;
        sWd[t] = w1 - w0;
        sR[t]  = root2[t];
    }
    if (t < 16) sB[t] = b2[t];
    if (t < BNODES) cur[t] = 0;
    __syncthreads();

    int cnt = cursor[b];
    if (cnt > CAP) cnt = CAP;
    unsigned long long* gp =
        (unsigned long long*)((char*)pkd + (size_t)b * CAPB);

    // single global pass: stage to LDS + histogram by local node
    for (int j = t; j < cnt; j += 512) {
        unsigned long long w = NTL(gp + j);
        updl[j] = w;
        atomicAdd(&cur[(int)(w >> 32) & 127], 1);
    }
    __syncthreads();

    // exclusive scan (128 entries, Hillis-Steele)
    int v = 0;
    if (t < BNODES) { v = cur[t]; rp[t] = v; }
    __syncthreads();
    for (int off = 1; off < BNODES; off <<= 1) {
        int x = 0;
        if (t < BNODES && t >= off) x = rp[t - off];
        __syncthreads();
        if (t < BNODES) rp[t] += x;
        __syncthreads();
    }
    if (t < BNODES) { int ex = rp[t] - v; rp[t] = ex; cur[t] = ex; }
    if (t == 0) rp[BNODES] = cnt;
    __syncthreads();

    // LDS counting sort into node order
    for (int j = t; j < cnt; j += 512) {
        unsigned long long w = updl[j];
        int pos = atomicAdd(&cur[(int)(w >> 32) & 127], 1);
        spk[pos] = (unsigned)w;
    }
    __syncthreads();

    // persist sorted pk (u32, in place over this bucket's region) + rptab
    unsigned* gs = (unsigned*)((char*)pkd + (size_t)b * CAPB);
    for (int j = t; j < cnt; j += 512) gs[j] = spk[j];
    if (t < RPW) rptab[b * RPW + t] = rp[t];

    // quad-split aggregation: 4 lanes/node, lane q owns features 4q..4q+3
    int node = t >> 2, q = t & 3;
    int n = (b << 7) + node;
    int beg = rp[node], end = rp[node + 1];
    int deg = end - beg;
    const float C = 1.0f / 32767.0f;

    float acc[4] = {0.0f, 0.0f, 0.0f, 0.0f};
    int j = beg;
    for (; j + 3 < end; j += 4) {
        unsigned p0 = spk[j], p1 = spk[j + 1], p2 = spk[j + 2], p3 = spk[j + 3];
        uint4 w0 = ldq_sc0(YPH1 + (size_t)(p0 & 0x1FFFFu) * 4 + q);
        uint4 w1 = ldq_sc0(YPH1 + (size_t)(p1 & 0x1FFFFu) * 4 + q);
        uint4 w2 = ldq_sc0(YPH1 + (size_t)(p2 & 0x1FFFFu) * 4 + q);
        uint4 w3 = ldq_sc0(YPH1 + (size_t)(p3 & 0x1FFFFu) * 4 + q);
        accq(acc, w0, (float)(p0 >> 17) * C);
        accq(acc, w1, (float)(p1 >> 17) * C);
        accq(acc, w2, (float)(p2 >> 17) * C);
        accq(acc, w3, (float)(p3 >> 17) * C);
    }
    for (; j < end; ++j) {
        unsigned p = spk[j];
        uint4 w = ldq_sc0(YPH1 + (size_t)(p & 0x1FFFFu) * 4 + q);
        accq(acc, w, (float)(p >> 17) * C);
    }

    if (n < N_NODES) {
        float inv = 1.0f / (deg > 0 ? (float)deg : 1.0f);
        float4 rr = ((const float4*)(R1 + (size_t)n * 16))[q];
        float hq[4], w;
        w = fmaf(acc[0], inv, rr.x); hq[0] = w > 0.0f ? w : expm1f(w);
        w = fmaf(acc[1], inv, rr.y); hq[1] = w > 0.0f ? w : expm1f(w);
        w = fmaf(acc[2], inv, rr.z); hq[2] = w > 0.0f ? w : expm1f(w);
        w = fmaf(acc[3], inv, rr.w); hq[3] = w > 0.0f ? w : expm1f(w);

        // reconstruct the full h row from the quad (16 shuffles)
        int qbase = (t & 63) & ~3;
        float h16[16];
#pragma unroll
        for (int p = 0; p < 4; ++p) {
            h16[4 * p + 0] = __shfl(hq[0], qbase + p);
            h16[4 * p + 1] = __shfl(hq[1], qbase + p);
            h16[4 * p + 2] = __shfl(hq[2], qbase + p);
            h16[4 * p + 3] = __shfl(hq[3], qbase + p);
        }

        // layer-2 transform: this lane computes 4 outputs o = 4q .. 4q+3
        float a0[4] = {0, 0, 0, 0}, a1[4] = {0, 0, 0, 0}, ar[4] = {0, 0, 0, 0};
        int o0 = q * 4;
#pragma unroll
        for (int f = 0; f < 16; ++f) {
            float hv = h16[f];
#pragma unroll
            for (int o = 0; o < 4; ++o) {
                a0[o] = fmaf(hv, sW0[f * 16 + o0 + o], a0[o]);
                a1[o] = fmaf(hv, sWd[f * 16 + o0 + o], a1[o]);
                ar[o] = fmaf(hv, sR [f * 16 + o0 + o], ar[o]);
            }
        }
        uint4 yw;
        yw.x = bf16_rne(a0[0]) | (bf16_rne(a1[0]) << 16);
        yw.y = bf16_rne(a0[1]) | (bf16_rne(a1[1]) << 16);
        yw.z = bf16_rne(a0[2]) | (bf16_rne(a1[2]) << 16);
        yw.w = bf16_rne(a0[3]) | (bf16_rne(a1[3]) << 16);
        ((uint4*)YPH2)[(size_t)n * 4 + q] = yw;
        float4 rv;
        rv.x = ar[0] + sB[o0 + 0];
        rv.y = ar[1] + sB[o0 + 1];
        rv.z = ar[2] + sB[o0 + 2];
        rv.w = ar[3] + sB[o0 + 3];
        ((float4*)R2)[(size_t)n * 4 + q] = rv;
    }
}

// ---------------------------------------------------------------------------
// K4 (block = 512, one block per bucket): node-sorted pk + rptab from K3;
// quad-split gather with sc0 loads, log-softmax over the quad.
__global__ __launch_bounds__(512)
void aggregate2(const int* __restrict__ rptab,
                const unsigned long long* __restrict__ pkd,
                const uint4* __restrict__ YPH2,
                const float* __restrict__ R2,
                float* __restrict__ out) {
    __shared__ int rp[RPW];
    int t = threadIdx.x, b = blockIdx.x;

    if (t < RPW) rp[t] = rptab[b * RPW + t];
    __syncthreads();

    const unsigned* pk = (const unsigned*)((const char*)pkd + (size_t)b * CAPB);
    int node = t >> 2, q = t & 3;
    int n = (b << 7) + node;
    int beg = rp[node], end = rp[node + 1];
    int deg = end - beg;
    const float C = 1.0f / 32767.0f;

    float acc[4] = {0.0f, 0.0f, 0.0f, 0.0f};
    int j = beg;
    for (; j + 3 < end; j += 4) {
        unsigned p0 = NTL(pk + j), p1 = NTL(pk + j + 1);
        unsigned p2 = NTL(pk + j + 2), p3 = NTL(pk + j + 3);
        uint4 w0 = ldq_sc0(YPH2 + (size_t)(p0 & 0x1FFFFu) * 4 + q);
        uint4 w1 = ldq_sc0(YPH2 + (size_t)(p1 & 0x1FFFFu) * 4 + q);
        uint4 w2 = ldq_sc0(YPH2 + (size_t)(p2 & 0x1FFFFu) * 4 + q);
        uint4 w3 = ldq_sc0(YPH2 + (size_t)(p3 & 0x1FFFFu) * 4 + q);
        accq(acc, w0, (float)(p0 >> 17) * C);
        accq(acc, w1, (float)(p1 >> 17) * C);
        accq(acc, w2, (float)(p2 >> 17) * C);
        accq(acc, w3, (float)(p3 >> 17) * C);
    }
    for (; j < end; ++j) {
        unsigned p = NTL(pk + j);
        uint4 w = ldq_sc0(YPH2 + (size_t)(p & 0x1FFFFu) * 4 + q);
        accq(acc, w, (float)(p >> 17) * C);
    }

    if (n < N_NODES) {
        float inv = 1.0f / (deg > 0 ? (float)deg : 1.0f);
        float4 rr = ((const float4*)R2)[(size_t)n * 4 + q];
        float v0 = fmaf(acc[0], inv, rr.x);
        float v1 = fmaf(acc[1], inv, rr.y);
        float v2 = fmaf(acc[2], inv, rr.z);
        float v3 = fmaf(acc[3], inv, rr.w);
        float m = fmaxf(fmaxf(v0, v1), fmaxf(v2, v3));
        m = fmaxf(m, __shfl_xor(m, 1));
        m = fmaxf(m, __shfl_xor(m, 2));
        float s = expf(v0 - m) + expf(v1 - m) + expf(v2 - m) + expf(v3 - m);
        s += __shfl_xor(s, 1);
        s += __shfl_xor(s, 2);
        float lse = m + logf(s);
        float4 ov = make_float4(v0 - lse, v1 - lse, v2 - lse, v3 - lse);
        ((float4*)out)[(size_t)n * 4 + q] = ov;
    }
}

// ---------------------------------------------------------------------------
extern "C" void kernel_launch(void* const* d_in, const int* in_sizes, int n_in,
                              void* d_out, int out_size, void* d_ws, size_t ws_size,
                              hipStream_t stream) {
    const float* x         = (const float*)d_in[0];
    const float* edge_attr = (const float*)d_in[1];
    const int*   edge_idx  = (const int*)d_in[2];
    const float* W1        = (const float*)d_in[3];
    const float* root1     = (const float*)d_in[4];
    const float* b1        = (const float*)d_in[5];
    const float* W2        = (const float*)d_in[6];
    const float* root2     = (const float*)d_in[7];
    const float* b2        = (const float*)d_in[8];
    float* out = (float*)d_out;

    const int* src = edge_idx;
    const int* dst = edge_idx + N_EDGES;

    // workspace layout (byte offsets, 16B aligned), total ~42.0 MB
    char* ws = (char*)d_ws;
    unsigned long long* pkd = (unsigned long long*)(ws); // 782*2560*8 = 16,015,360
    unsigned* YPH1 = (unsigned*)(ws + 16015360);         //  6,400,000
    float*    R1   = (float*)(ws + 22415360);            //  6,400,000
    unsigned* YPH2 = (unsigned*)(ws + 28815360);         //  6,400,000
    float*    R2   = (float*)(ws + 35215360);            //  6,400,000
    int*      cursor = (int*)(ws + 41615360);            //      3,128
    int*      rptab  = (int*)(ws + 41618496);            //    403,512

    hipMemsetAsync(cursor, 0, NBUK * sizeof(int), stream);

    fused_transform_scatter<<<dim3(NCHUNK + NTBLK), 1024, SM_TOTAL, stream>>>(
        x, W1, root1, b1, YPH1, R1, src, dst, edge_attr, cursor, pkd);

    aggregate1<<<dim3(NBUK), 512, 0, stream>>>(
        cursor, pkd, rptab, (const uint4*)YPH1, R1, W2, root2, b2, YPH2, R2);

    aggregate2<<<dim3(NBUK), 512, 0, stream>>>(
        rptab, pkd, (const uint4*)YPH2, R2, out);
}

// Round 11
// 189.386 us; speedup vs baseline: 1.0414x; 1.0414x over previous
//
#include <hip/hip_runtime.h>
#include <math.h>

#define N_NODES 100000
#define N_EDGES 1600000
#define NBUK 782                  // buckets of 128 nodes (dst >> 7); 782*128 = 100096
#define BNODES 128
#define CAP 2560                  // slots per bucket (mean ~2046, ~11 sigma margin)
#define CAPB (CAP * 8)            // bucket region bytes in the u64 pkd buffer
#define NCHUNK 512                // scatter chunk blocks
#define CPE 3125                  // edges per chunk (512*3125 = 1.6M exact)
#define NTBLK 1563                // transform blocks (1563*1024 >= 1.6M node-feats)
#define GRID1 2075                // interleaved grid: 512 scatter + 1563 transform
#define WS 52                     // transposed-weight LDS stride (16B-aligned)
#define RPW (BNODES + 1)          // rowptr entries per bucket (129)

// scatter-path dynamic LDS layout (60,352 B; transform path needs 10,048)
#define SM_LCUR  0                // int[NBUK]   3128
#define SM_GBASE 3128             // int[NBUK]   3128
#define SM_SC    6256             // int[1024]   4096
#define SM_UPDL  10352            // u64[CPE]   25000 (8-aligned)
#define SM_SPDL  35352            // u64[CPE]   25000
#define SM_TOTAL 60352

#define NTL(p) __builtin_nontemporal_load(p)

// ---------------------------------------------------------------------------
__device__ __forceinline__ unsigned bf16_rne(float x) {
    unsigned u = __float_as_uint(x);
    return (u + 0x7FFFu + ((u >> 16) & 1u)) >> 16;
}

// accumulate one 16B chunk (4 packed bf16 pairs) with weight uu
__device__ __forceinline__ void accq(float acc[4], uint4 w, float uu) {
    acc[0] += fmaf(uu, __uint_as_float(w.x & 0xFFFF0000u), __uint_as_float(w.x << 16));
    acc[1] += fmaf(uu, __uint_as_float(w.y & 0xFFFF0000u), __uint_as_float(w.y << 16));
    acc[2] += fmaf(uu, __uint_as_float(w.z & 0xFFFF0000u), __uint_as_float(w.z << 16));
    acc[3] += fmaf(uu, __uint_as_float(w.w & 0xFFFF0000u), __uint_as_float(w.w << 16));
}

// ---------------------------------------------------------------------------
// K1 merged, INTERLEAVED roles: bid%4==0 (bid<2048) -> scatter chunk bid>>2;
// otherwise transform. Interleaving co-schedules the LDS/barrier-heavy
// scatter with the VALU-heavy transform on every CU (the ordered split ran
// them back-to-back). Scan is wave-level shfl (3 barriers vs 21).
__global__ __launch_bounds__(1024)
void fused_transform_scatter(const float* __restrict__ X,
                             const float* __restrict__ W,
                             const float* __restrict__ root,
                             const float* __restrict__ bias,
                             unsigned* __restrict__ YPH, float* __restrict__ R,
                             const int* __restrict__ src,
                             const int* __restrict__ dst,
                             const float* __restrict__ u,
                             int* __restrict__ cursor,
                             unsigned long long* __restrict__ pkd) {
    extern __shared__ char smem[];
    int t = threadIdx.x;
    int bid = blockIdx.x;
    bool is_scatter = (bid < 2048) && ((bid & 3) == 0);
    if (is_scatter) {
        // ------------------------------------------------ scatter path
        int c = bid >> 2;
        int* lcur = (int*)(smem + SM_LCUR);
        int* gbase = (int*)(smem + SM_GBASE);
        int* sc = (int*)(smem + SM_SC);
        unsigned long long* updl = (unsigned long long*)(smem + SM_UPDL);
        unsigned long long* spdl = (unsigned long long*)(smem + SM_SPDL);

        for (int i = t; i < NBUK; i += 1024) lcur[i] = 0;
        __syncthreads();
        for (int j = t; j < CPE; j += 1024) {
            int e = c * CPE + j;
            int d = NTL(dst + e);
            float uu = NTL(u + e);
            uu = uu < 0.0f ? 0.0f : (uu > 1.0f ? 1.0f : uu);
            int u15 = (int)fmaf(uu, 32767.0f, 0.5f);
            unsigned pk32 = (unsigned)NTL(src + e) | ((unsigned)u15 << 17);
            updl[j] = (unsigned long long)pk32 |
                      ((unsigned long long)(unsigned)d << 32);
            atomicAdd(&lcur[d >> 7], 1);
        }
        __syncthreads();

        // wave-level exclusive scan over lcur[0..NBUK)
        int lane = t & 63, wid = t >> 6;
        int v = (t < NBUK) ? lcur[t] : 0;
        int inc = v;
#pragma unroll
        for (int off = 1; off < 64; off <<= 1) {
            int x = __shfl_up(inc, off);
            if (lane >= off) inc += x;
        }
        if (lane == 63) sc[wid] = inc;
        __syncthreads();
        if (wid == 0) {
            int s = (lane < 16) ? sc[lane] : 0;
            int sinc = s;
#pragma unroll
            for (int off = 1; off < 16; off <<= 1) {
                int x = __shfl_up(sinc, off);
                if (lane >= off) sinc += x;
            }
            if (lane < 16) sc[lane] = sinc - s;   // exclusive wave prefix
        }
        __syncthreads();
        if (t < NBUK) {
            int ex = sc[wid] + inc - v;           // exclusive scan value
            lcur[t] = ex;
            int base = t * CAP + atomicAdd(&cursor[t], v);
            gbase[t] = base - ex;
        }
        __syncthreads();

        for (int j = t; j < CPE; j += 1024) {
            unsigned long long w = updl[j];
            int b = (int)(w >> 39) & 0x3FF;
            int p = atomicAdd(&lcur[b], 1);
            spdl[p] = w;
        }
        __syncthreads();

        for (int j = t; j < CPE; j += 1024) {
            unsigned long long w = spdl[j];
            int b = (int)(w >> 39) & 0x3FF;
            int g = gbase[b] + j;
            if (g < (b + 1) * CAP)
                pkd[g] = w;
        }
    } else {
        // ------------------------------------------------ transform path
        float* sW0 = (float*)smem;
        float* sWd = (float*)(smem + 3328);
        float* sR  = (float*)(smem + 6656);
        float* sB  = (float*)(smem + 9984);
        int tb = (bid < 2048) ? (bid - 1 - (bid >> 2)) : (1536 + bid - 2048);
        for (int i = t; i < 48 * 16; i += 1024) {
            int f = i >> 4, o = i & 15;
            float w0 = W[i];
            float w1 = W[48 * 16 + i];
            sW0[o * WS + f] = w0;
            sWd[o * WS + f] = w1 - w0;
            sR[o * WS + f]  = root[i];
        }
        if (t < 16) sB[t] = bias[t];
        __syncthreads();

        int idx = tb * 1024 + t;
        int n = idx >> 4;
        int o = idx & 15;
        if (n >= N_NODES) return;

        const float4* xr  = (const float4*)(X + (long)n * 48);
        const float4* w0p = (const float4*)(sW0 + o * WS);
        const float4* wdp = (const float4*)(sWd + o * WS);
        const float4* wrp = (const float4*)(sR  + o * WS);
        float a0 = 0.0f, a1 = 0.0f, ar = 0.0f;
#pragma unroll
        for (int fc = 0; fc < 12; ++fc) {
            float4 xv = xr[fc];
            float4 w0 = w0p[fc];
            float4 wd = wdp[fc];
            float4 wr = wrp[fc];
            a0 = fmaf(xv.x, w0.x, a0); a0 = fmaf(xv.y, w0.y, a0);
            a0 = fmaf(xv.z, w0.z, a0); a0 = fmaf(xv.w, w0.w, a0);
            a1 = fmaf(xv.x, wd.x, a1); a1 = fmaf(xv.y, wd.y, a1);
            a1 = fmaf(xv.z, wd.z, a1); a1 = fmaf(xv.w, wd.w, a1);
            ar = fmaf(xv.x, wr.x, ar); ar = fmaf(xv.y, wr.y, ar);
            ar = fmaf(xv.z, wr.z, ar); ar = fmaf(xv.w, wr.w, ar);
        }
        YPH[idx] = bf16_rne(a0) | (bf16_rne(a1) << 16);
        R[idx]   = ar + sB[o];
    }
}

// ---------------------------------------------------------------------------
// K3 (block = 512, one block per 128-node bucket; EXACT round-8 structure):
// stage + histogram + scan + LDS counting sort; sorted pk persisted in place
// + rptab. Aggregation: 4-lane quad-split with plain NTL 16B gathers.
__global__ __launch_bounds__(512)
void aggregate1(const int* __restrict__ cursor,
                unsigned long long* __restrict__ pkd,
                int* __restrict__ rptab,
                const uint4* __restrict__ YPH1,
                const float* __restrict__ R1,
                const float* __restrict__ W2,
                const float* __restrict__ root2,
                const float* __restrict__ b2,
                unsigned* __restrict__ YPH2,
                float* __restrict__ R2) {
    __shared__ unsigned long long updl[CAP];   // 20480 B
    __shared__ unsigned spk[CAP];              // 10240 B
    __shared__ int rp[RPW];
    __shared__ int cur[BNODES];
    __shared__ float sW0[256], sWd[256], sR[256], sB[16];
    int t = threadIdx.x, b = blockIdx.x;

    if (t < 256) {
        float w0 = W2[t], w1 = W2[256 + t];
        sW0[t] = w0;
        sWd[t] = w1 - w0;
        sR[t]  = root2[t];
    }
    if (t < 16) sB[t] = b2[t];
    if (t < BNODES) cur[t] = 0;
    __syncthreads();

    int cnt = cursor[b];
    if (cnt > CAP) cnt = CAP;
    unsigned long long* gp =
        (unsigned long long*)((char*)pkd + (size_t)b * CAPB);

    // single global pass: stage to LDS + histogram by local node
    for (int j = t; j < cnt; j += 512) {
        unsigned long long w = NTL(gp + j);
        updl[j] = w;
        atomicAdd(&cur[(int)(w >> 32) & 127], 1);
    }
    __syncthreads();

    // exclusive scan (128 entries, Hillis-Steele)
    int v = 0;
    if (t < BNODES) { v = cur[t]; rp[t] = v; }
    __syncthreads();
    for (int off = 1; off < BNODES; off <<= 1) {
        int x = 0;
        if (t < BNODES && t >= off) x = rp[t - off];
        __syncthreads();
        if (t < BNODES) rp[t] += x;
        __syncthreads();
    }
    if (t < BNODES) { int ex = rp[t] - v; rp[t] = ex; cur[t] = ex; }
    if (t == 0) rp[BNODES] = cnt;
    __syncthreads();

    // LDS counting sort into node order
    for (int j = t; j < cnt; j += 512) {
        unsigned long long w = updl[j];
        int pos = atomicAdd(&cur[(int)(w >> 32) & 127], 1);
        spk[pos] = (unsigned)w;
    }
    __syncthreads();

    // persist sorted pk (u32, in place over this bucket's region) + rptab
    unsigned* gs = (unsigned*)((char*)pkd + (size_t)b * CAPB);
    for (int j = t; j < cnt; j += 512) gs[j] = spk[j];
    if (t < RPW) rptab[b * RPW + t] = rp[t];

    // quad-split aggregation: 4 lanes/node, lane q owns features 4q..4q+3
    int node = t >> 2, q = t & 3;
    int n = (b << 7) + node;
    int beg = rp[node], end = rp[node + 1];
    int deg = end - beg;
    const float C = 1.0f / 32767.0f;

    float acc[4] = {0.0f, 0.0f, 0.0f, 0.0f};
    int j = beg;
    for (; j + 3 < end; j += 4) {
        unsigned p0 = spk[j], p1 = spk[j + 1], p2 = spk[j + 2], p3 = spk[j + 3];
        uint4 w0 = YPH1[(size_t)(p0 & 0x1FFFFu) * 4 + q];
        uint4 w1 = YPH1[(size_t)(p1 & 0x1FFFFu) * 4 + q];
        uint4 w2 = YPH1[(size_t)(p2 & 0x1FFFFu) * 4 + q];
        uint4 w3 = YPH1[(size_t)(p3 & 0x1FFFFu) * 4 + q];
        accq(acc, w0, (float)(p0 >> 17) * C);
        accq(acc, w1, (float)(p1 >> 17) * C);
        accq(acc, w2, (float)(p2 >> 17) * C);
        accq(acc, w3, (float)(p3 >> 17) * C);
    }
    for (; j < end; ++j) {
        unsigned p = spk[j];
        uint4 w = YPH1[(size_t)(p & 0x1FFFFu) * 4 + q];
        accq(acc, w, (float)(p >> 17) * C);
    }

    if (n < N_NODES) {
        float inv = 1.0f / (deg > 0 ? (float)deg : 1.0f);
        float4 rr = ((const float4*)(R1 + (size_t)n * 16))[q];
        float hq[4], w;
        w = fmaf(acc[0], inv, rr.x); hq[0] = w > 0.0f ? w : expm1f(w);
        w = fmaf(acc[1], inv, rr.y); hq[1] = w > 0.0f ? w : expm1f(w);
        w = fmaf(acc[2], inv, rr.z); hq[2] = w > 0.0f ? w : expm1f(w);
        w = fmaf(acc[3], inv, rr.w); hq[3] = w > 0.0f ? w : expm1f(w);

        // reconstruct the full h row from the quad (16 shuffles)
        int qbase = (t & 63) & ~3;
        float h16[16];
#pragma unroll
        for (int p = 0; p < 4; ++p) {
            h16[4 * p + 0] = __shfl(hq[0], qbase + p);
            h16[4 * p + 1] = __shfl(hq[1], qbase + p);
            h16[4 * p + 2] = __shfl(hq[2], qbase + p);
            h16[4 * p + 3] = __shfl(hq[3], qbase + p);
        }

        // layer-2 transform: this lane computes 4 outputs o = 4q .. 4q+3
        float a0[4] = {0, 0, 0, 0}, a1[4] = {0, 0, 0, 0}, ar[4] = {0, 0, 0, 0};
        int o0 = q * 4;
#pragma unroll
        for (int f = 0; f < 16; ++f) {
            float hv = h16[f];
#pragma unroll
            for (int o = 0; o < 4; ++o) {
                a0[o] = fmaf(hv, sW0[f * 16 + o0 + o], a0[o]);
                a1[o] = fmaf(hv, sWd[f * 16 + o0 + o], a1[o]);
                ar[o] = fmaf(hv, sR [f * 16 + o0 + o], ar[o]);
            }
        }
        uint4 yw;
        yw.x = bf16_rne(a0[0]) | (bf16_rne(a1[0]) << 16);
        yw.y = bf16_rne(a0[1]) | (bf16_rne(a1[1]) << 16);
        yw.z = bf16_rne(a0[2]) | (bf16_rne(a1[2]) << 16);
        yw.w = bf16_rne(a0[3]) | (bf16_rne(a1[3]) << 16);
        ((uint4*)YPH2)[(size_t)n * 4 + q] = yw;
        float4 rv;
        rv.x = ar[0] + sB[o0 + 0];
        rv.y = ar[1] + sB[o0 + 1];
        rv.z = ar[2] + sB[o0 + 2];
        rv.w = ar[3] + sB[o0 + 3];
        ((float4*)R2)[(size_t)n * 4 + q] = rv;
    }
}

// ---------------------------------------------------------------------------
// K4 (block = 512, one block per bucket): node-sorted pk + rptab from K3;
// quad-split gather (plain NTL), log-softmax over the quad.
__global__ __launch_bounds__(512)
void aggregate2(const int* __restrict__ rptab,
                const unsigned long long* __restrict__ pkd,
                const uint4* __restrict__ YPH2,
                const float* __restrict__ R2,
                float* __restrict__ out) {
    __shared__ int rp[RPW];
    int t = threadIdx.x, b = blockIdx.x;

    if (t < RPW) rp[t] = rptab[b * RPW + t];
    __syncthreads();

    const unsigned* pk = (const unsigned*)((const char*)pkd + (size_t)b * CAPB);
    int node = t >> 2, q = t & 3;
    int n = (b << 7) + node;
    int beg = rp[node], end = rp[node + 1];
    int deg = end - beg;
    const float C = 1.0f / 32767.0f;

    float acc[4] = {0.0f, 0.0f, 0.0f, 0.0f};
    int j = beg;
    for (; j + 3 < end; j += 4) {
        unsigned p0 = NTL(pk + j), p1 = NTL(pk + j + 1);
        unsigned p2 = NTL(pk + j + 2), p3 = NTL(pk + j + 3);
        uint4 w0 = YPH2[(size_t)(p0 & 0x1FFFFu) * 4 + q];
        uint4 w1 = YPH2[(size_t)(p1 & 0x1FFFFu) * 4 + q];
        uint4 w2 = YPH2[(size_t)(p2 & 0x1FFFFu) * 4 + q];
        uint4 w3 = YPH2[(size_t)(p3 & 0x1FFFFu) * 4 + q];
        accq(acc, w0, (float)(p0 >> 17) * C);
        accq(acc, w1, (float)(p1 >> 17) * C);
        accq(acc, w2, (float)(p2 >> 17) * C);
        accq(acc, w3, (float)(p3 >> 17) * C);
    }
    for (; j < end; ++j) {
        unsigned p = NTL(pk + j);
        uint4 w = YPH2[(size_t)(p & 0x1FFFFu) * 4 + q];
        accq(acc, w, (float)(p >> 17) * C);
    }

    if (n < N_NODES) {
        float inv = 1.0f / (deg > 0 ? (float)deg : 1.0f);
        float4 rr = ((const float4*)R2)[(size_t)n * 4 + q];
        float v0 = fmaf(acc[0], inv, rr.x);
        float v1 = fmaf(acc[1], inv, rr.y);
        float v2 = fmaf(acc[2], inv, rr.z);
        float v3 = fmaf(acc[3], inv, rr.w);
        float m = fmaxf(fmaxf(v0, v1), fmaxf(v2, v3));
        m = fmaxf(m, __shfl_xor(m, 1));
        m = fmaxf(m, __shfl_xor(m, 2));
        float s = expf(v0 - m) + expf(v1 - m) + expf(v2 - m) + expf(v3 - m);
        s += __shfl_xor(s, 1);
        s += __shfl_xor(s, 2);
        float lse = m + logf(s);
        float4 ov = make_float4(v0 - lse, v1 - lse, v2 - lse, v3 - lse);
        ((float4*)out)[(size_t)n * 4 + q] = ov;
    }
}

// ---------------------------------------------------------------------------
extern "C" void kernel_launch(void* const* d_in, const int* in_sizes, int n_in,
                              void* d_out, int out_size, void* d_ws, size_t ws_size,
                              hipStream_t stream) {
    const float* x         = (const float*)d_in[0];
    const float* edge_attr = (const float*)d_in[1];
    const int*   edge_idx  = (const int*)d_in[2];
    const float* W1        = (const float*)d_in[3];
    const float* root1     = (const float*)d_in[4];
    const float* b1        = (const float*)d_in[5];
    const float* W2        = (const float*)d_in[6];
    const float* root2     = (const float*)d_in[7];
    const float* b2        = (const float*)d_in[8];
    float* out = (float*)d_out;

    const int* src = edge_idx;
    const int* dst = edge_idx + N_EDGES;

    // workspace layout (byte offsets, 16B aligned), total ~42.0 MB
    char* ws = (char*)d_ws;
    unsigned long long* pkd = (unsigned long long*)(ws); // 782*2560*8 = 16,015,360
    unsigned* YPH1 = (unsigned*)(ws + 16015360);         //  6,400,000
    float*    R1   = (float*)(ws + 22415360);            //  6,400,000
    unsigned* YPH2 = (unsigned*)(ws + 28815360);         //  6,400,000
    float*    R2   = (float*)(ws + 35215360);            //  6,400,000
    int*      cursor = (int*)(ws + 41615360);            //      3,128
    int*      rptab  = (int*)(ws + 41618496);            //    403,512

    hipMemsetAsync(cursor, 0, NBUK * sizeof(int), stream);

    fused_transform_scatter<<<dim3(GRID1), 1024, SM_TOTAL, stream>>>(
        x, W1, root1, b1, YPH1, R1, src, dst, edge_attr, cursor, pkd);

    aggregate1<<<dim3(NBUK), 512, 0, stream>>>(
        cursor, pkd, rptab, (const uint4*)YPH1, R1, W2, root2, b2, YPH2, R2);

    aggregate2<<<dim3(NBUK), 512, 0, stream>>>(
        rptab, pkd, (const uint4*)YPH2, R2, out);
}

// Round 12
// 177.892 us; speedup vs baseline: 1.1087x; 1.0646x over previous
//
#include <hip/hip_runtime.h>
#include <math.h>

#define N_NODES 100000
#define N_EDGES 1600000
#define NBUK 782                  // buckets of 128 nodes (dst >> 7); 782*128 = 100096
#define BNODES 128
#define CAP 2560                  // slots per bucket (mean ~2046, ~11 sigma margin)
#define CAPB (CAP * 8)            // bucket region bytes in the u64 pkd buffer
#define NCHUNK 512                // scatter chunk blocks
#define CPE 3125                  // edges per chunk (512*3125 = 1.6M exact)
#define NTBLK 1563                // transform blocks (1563*1024 >= 1.6M node-feats)
#define WS 52                     // transposed-weight LDS stride (16B-aligned)
#define RPW (BNODES + 1)          // rowptr entries per bucket (129)

// scatter-path dynamic LDS layout (60,352 B; transform path needs 10,048)
#define SM_LCUR  0                // int[NBUK]   3128
#define SM_GBASE 3128             // int[NBUK]   3128
#define SM_SC    6256             // int[1024]   4096
#define SM_UPDL  10352            // u64[CPE]   25000 (8-aligned)
#define SM_SPDL  35352            // u64[CPE]   25000
#define SM_TOTAL 60352

#define NTL(p) __builtin_nontemporal_load(p)

// ---------------------------------------------------------------------------
__device__ __forceinline__ unsigned bf16_rne(float x) {
    unsigned u = __float_as_uint(x);
    return (u + 0x7FFFu + ((u >> 16) & 1u)) >> 16;
}

// accumulate one 16B chunk (4 packed bf16 pairs) with weight uu
__device__ __forceinline__ void accq(float acc[4], uint4 w, float uu) {
    acc[0] += fmaf(uu, __uint_as_float(w.x & 0xFFFF0000u), __uint_as_float(w.x << 16));
    acc[1] += fmaf(uu, __uint_as_float(w.y & 0xFFFF0000u), __uint_as_float(w.y << 16));
    acc[2] += fmaf(uu, __uint_as_float(w.z & 0xFFFF0000u), __uint_as_float(w.z << 16));
    acc[3] += fmaf(uu, __uint_as_float(w.w & 0xFFFF0000u), __uint_as_float(w.w << 16));
}

// ---------------------------------------------------------------------------
// K1 merged (round-8 ORDERED roles: scatter = blocks [0,NCHUNK), transform
// after — interleaving regressed occupancy 33->23% in r11). Only delta vs
// round 8: the scatter's bucket scan is wave-level shfl (3 barriers vs 21).
__global__ __launch_bounds__(1024)
void fused_transform_scatter(const float* __restrict__ X,
                             const float* __restrict__ W,
                             const float* __restrict__ root,
                             const float* __restrict__ bias,
                             unsigned* __restrict__ YPH, float* __restrict__ R,
                             const int* __restrict__ src,
                             const int* __restrict__ dst,
                             const float* __restrict__ u,
                             int* __restrict__ cursor,
                             unsigned long long* __restrict__ pkd) {
    extern __shared__ char smem[];
    int t = threadIdx.x;
    if (blockIdx.x < NCHUNK) {
        // ------------------------------------------------ scatter path
        int c = blockIdx.x;
        int* lcur = (int*)(smem + SM_LCUR);
        int* gbase = (int*)(smem + SM_GBASE);
        int* sc = (int*)(smem + SM_SC);
        unsigned long long* updl = (unsigned long long*)(smem + SM_UPDL);
        unsigned long long* spdl = (unsigned long long*)(smem + SM_SPDL);

        for (int i = t; i < NBUK; i += 1024) lcur[i] = 0;
        __syncthreads();
        for (int j = t; j < CPE; j += 1024) {
            int e = c * CPE + j;
            int d = NTL(dst + e);
            float uu = NTL(u + e);
            uu = uu < 0.0f ? 0.0f : (uu > 1.0f ? 1.0f : uu);
            int u15 = (int)fmaf(uu, 32767.0f, 0.5f);
            unsigned pk32 = (unsigned)NTL(src + e) | ((unsigned)u15 << 17);
            updl[j] = (unsigned long long)pk32 |
                      ((unsigned long long)(unsigned)d << 32);
            atomicAdd(&lcur[d >> 7], 1);
        }
        __syncthreads();

        // wave-level exclusive scan over lcur[0..NBUK)
        int lane = t & 63, wid = t >> 6;
        int v = (t < NBUK) ? lcur[t] : 0;
        int inc = v;
#pragma unroll
        for (int off = 1; off < 64; off <<= 1) {
            int x = __shfl_up(inc, off);
            if (lane >= off) inc += x;
        }
        if (lane == 63) sc[wid] = inc;
        __syncthreads();
        if (wid == 0) {
            int s = (lane < 16) ? sc[lane] : 0;
            int sinc = s;
#pragma unroll
            for (int off = 1; off < 16; off <<= 1) {
                int x = __shfl_up(sinc, off);
                if (lane >= off) sinc += x;
            }
            if (lane < 16) sc[lane] = sinc - s;   // exclusive wave prefix
        }
        __syncthreads();
        if (t < NBUK) {
            int ex = sc[wid] + inc - v;           // exclusive scan value
            lcur[t] = ex;
            int base = t * CAP + atomicAdd(&cursor[t], v);
            gbase[t] = base - ex;
        }
        __syncthreads();

        for (int j = t; j < CPE; j += 1024) {
            unsigned long long w = updl[j];
            int b = (int)(w >> 39) & 0x3FF;
            int p = atomicAdd(&lcur[b], 1);
            spdl[p] = w;
        }
        __syncthreads();

        for (int j = t; j < CPE; j += 1024) {
            unsigned long long w = spdl[j];
            int b = (int)(w >> 39) & 0x3FF;
            int g = gbase[b] + j;
            if (g < (b + 1) * CAP)
                pkd[g] = w;
        }
    } else {
        // ------------------------------------------------ transform path
        float* sW0 = (float*)smem;
        float* sWd = (float*)(smem + 3328);
        float* sR  = (float*)(smem + 6656);
        float* sB  = (float*)(smem + 9984);
        int bid = blockIdx.x - NCHUNK;
        for (int i = t; i < 48 * 16; i += 1024) {
            int f = i >> 4, o = i & 15;
            float w0 = W[i];
            float w1 = W[48 * 16 + i];
            sW0[o * WS + f] = w0;
            sWd[o * WS + f] = w1 - w0;
            sR[o * WS + f]  = root[i];
        }
        if (t < 16) sB[t] = bias[t];
        __syncthreads();

        int idx = bid * 1024 + t;
        int n = idx >> 4;
        int o = idx & 15;
        if (n >= N_NODES) return;

        const float4* xr  = (const float4*)(X + (long)n * 48);
        const float4* w0p = (const float4*)(sW0 + o * WS);
        const float4* wdp = (const float4*)(sWd + o * WS);
        const float4* wrp = (const float4*)(sR  + o * WS);
        float a0 = 0.0f, a1 = 0.0f, ar = 0.0f;
#pragma unroll
        for (int fc = 0; fc < 12; ++fc) {
            float4 xv = xr[fc];
            float4 w0 = w0p[fc];
            float4 wd = wdp[fc];
            float4 wr = wrp[fc];
            a0 = fmaf(xv.x, w0.x, a0); a0 = fmaf(xv.y, w0.y, a0);
            a0 = fmaf(xv.z, w0.z, a0); a0 = fmaf(xv.w, w0.w, a0);
            a1 = fmaf(xv.x, wd.x, a1); a1 = fmaf(xv.y, wd.y, a1);
            a1 = fmaf(xv.z, wd.z, a1); a1 = fmaf(xv.w, wd.w, a1);
            ar = fmaf(xv.x, wr.x, ar); ar = fmaf(xv.y, wr.y, ar);
            ar = fmaf(xv.z, wr.z, ar); ar = fmaf(xv.w, wr.w, ar);
        }
        YPH[idx] = bf16_rne(a0) | (bf16_rne(a1) << 16);
        R[idx]   = ar + sB[o];
    }
}

// ---------------------------------------------------------------------------
// K3 (block = 512, one block per 128-node bucket; EXACT round-8 structure):
// stage + histogram + scan + LDS counting sort; sorted pk persisted in place
// + rptab. Aggregation: 4-lane quad-split with plain 16B gathers.
__global__ __launch_bounds__(512)
void aggregate1(const int* __restrict__ cursor,
                unsigned long long* __restrict__ pkd,
                int* __restrict__ rptab,
                const uint4* __restrict__ YPH1,
                const float* __restrict__ R1,
                const float* __restrict__ W2,
                const float* __restrict__ root2,
                const float* __restrict__ b2,
                unsigned* __restrict__ YPH2,
                float* __restrict__ R2) {
    __shared__ unsigned long long updl[CAP];   // 20480 B
    __shared__ unsigned spk[CAP];              // 10240 B
    __shared__ int rp[RPW];
    __shared__ int cur[BNODES];
    __shared__ float sW0[256], sWd[256], sR[256], sB[16];
    int t = threadIdx.x, b = blockIdx.x;

    if (t < 256) {
        float w0 = W2[t], w1 = W2[256 + t];
        sW0[t] = w0;
        sWd[t] = w1 - w0;
        sR[t]  = root2[t];
    }
    if (t < 16) sB[t] = b2[t];
    if (t < BNODES) cur[t] = 0;
    __syncthreads();

    int cnt = cursor[b];
    if (cnt > CAP) cnt = CAP;
    unsigned long long* gp =
        (unsigned long long*)((char*)pkd + (size_t)b * CAPB);

    // single global pass: stage to LDS + histogram by local node
    for (int j = t; j < cnt; j += 512) {
        unsigned long long w = NTL(gp + j);
        updl[j] = w;
        atomicAdd(&cur[(int)(w >> 32) & 127], 1);
    }
    __syncthreads();

    // exclusive scan (128 entries, Hillis-Steele)
    int v = 0;
    if (t < BNODES) { v = cur[t]; rp[t] = v; }
    __syncthreads();
    for (int off = 1; off < BNODES; off <<= 1) {
        int x = 0;
        if (t < BNODES && t >= off) x = rp[t - off];
        __syncthreads();
        if (t < BNODES) rp[t] += x;
        __syncthreads();
    }
    if (t < BNODES) { int ex = rp[t] - v; rp[t] = ex; cur[t] = ex; }
    if (t == 0) rp[BNODES] = cnt;
    __syncthreads();

    // LDS counting sort into node order
    for (int j = t; j < cnt; j += 512) {
        unsigned long long w = updl[j];
        int pos = atomicAdd(&cur[(int)(w >> 32) & 127], 1);
        spk[pos] = (unsigned)w;
    }
    __syncthreads();

    // persist sorted pk (u32, in place over this bucket's region) + rptab
    unsigned* gs = (unsigned*)((char*)pkd + (size_t)b * CAPB);
    for (int j = t; j < cnt; j += 512) gs[j] = spk[j];
    if (t < RPW) rptab[b * RPW + t] = rp[t];

    // quad-split aggregation: 4 lanes/node, lane q owns features 4q..4q+3
    int node = t >> 2, q = t & 3;
    int n = (b << 7) + node;
    int beg = rp[node], end = rp[node + 1];
    int deg = end - beg;
    const float C = 1.0f / 32767.0f;

    float acc[4] = {0.0f, 0.0f, 0.0f, 0.0f};
    int j = beg;
    for (; j + 3 < end; j += 4) {
        unsigned p0 = spk[j], p1 = spk[j + 1], p2 = spk[j + 2], p3 = spk[j + 3];
        uint4 w0 = YPH1[(size_t)(p0 & 0x1FFFFu) * 4 + q];
        uint4 w1 = YPH1[(size_t)(p1 & 0x1FFFFu) * 4 + q];
        uint4 w2 = YPH1[(size_t)(p2 & 0x1FFFFu) * 4 + q];
        uint4 w3 = YPH1[(size_t)(p3 & 0x1FFFFu) * 4 + q];
        accq(acc, w0, (float)(p0 >> 17) * C);
        accq(acc, w1, (float)(p1 >> 17) * C);
        accq(acc, w2, (float)(p2 >> 17) * C);
        accq(acc, w3, (float)(p3 >> 17) * C);
    }
    for (; j < end; ++j) {
        unsigned p = spk[j];
        uint4 w = YPH1[(size_t)(p & 0x1FFFFu) * 4 + q];
        accq(acc, w, (float)(p >> 17) * C);
    }

    if (n < N_NODES) {
        float inv = 1.0f / (deg > 0 ? (float)deg : 1.0f);
        float4 rr = ((const float4*)(R1 + (size_t)n * 16))[q];
        float hq[4], w;
        w = fmaf(acc[0], inv, rr.x); hq[0] = w > 0.0f ? w : expm1f(w);
        w = fmaf(acc[1], inv, rr.y); hq[1] = w > 0.0f ? w : expm1f(w);
        w = fmaf(acc[2], inv, rr.z); hq[2] = w > 0.0f ? w : expm1f(w);
        w = fmaf(acc[3], inv, rr.w); hq[3] = w > 0.0f ? w : expm1f(w);

        // reconstruct the full h row from the quad (16 shuffles)
        int qbase = (t & 63) & ~3;
        float h16[16];
#pragma unroll
        for (int p = 0; p < 4; ++p) {
            h16[4 * p + 0] = __shfl(hq[0], qbase + p);
            h16[4 * p + 1] = __shfl(hq[1], qbase + p);
            h16[4 * p + 2] = __shfl(hq[2], qbase + p);
            h16[4 * p + 3] = __shfl(hq[3], qbase + p);
        }

        // layer-2 transform: this lane computes 4 outputs o = 4q .. 4q+3
        float a0[4] = {0, 0, 0, 0}, a1[4] = {0, 0, 0, 0}, ar[4] = {0, 0, 0, 0};
        int o0 = q * 4;
#pragma unroll
        for (int f = 0; f < 16; ++f) {
            float hv = h16[f];
#pragma unroll
            for (int o = 0; o < 4; ++o) {
                a0[o] = fmaf(hv, sW0[f * 16 + o0 + o], a0[o]);
                a1[o] = fmaf(hv, sWd[f * 16 + o0 + o], a1[o]);
                ar[o] = fmaf(hv, sR [f * 16 + o0 + o], ar[o]);
            }
        }
        uint4 yw;
        yw.x = bf16_rne(a0[0]) | (bf16_rne(a1[0]) << 16);
        yw.y = bf16_rne(a0[1]) | (bf16_rne(a1[1]) << 16);
        yw.z = bf16_rne(a0[2]) | (bf16_rne(a1[2]) << 16);
        yw.w = bf16_rne(a0[3]) | (bf16_rne(a1[3]) << 16);
        ((uint4*)YPH2)[(size_t)n * 4 + q] = yw;
        float4 rv;
        rv.x = ar[0] + sB[o0 + 0];
        rv.y = ar[1] + sB[o0 + 1];
        rv.z = ar[2] + sB[o0 + 2];
        rv.w = ar[3] + sB[o0 + 3];
        ((float4*)R2)[(size_t)n * 4 + q] = rv;
    }
}

// ---------------------------------------------------------------------------
// K4 (block = 512, one block per bucket): node-sorted pk + rptab from K3;
// quad-split gather, log-softmax over the quad.
__global__ __launch_bounds__(512)
void aggregate2(const int* __restrict__ rptab,
                const unsigned long long* __restrict__ pkd,
                const uint4* __restrict__ YPH2,
                const float* __restrict__ R2,
                float* __restrict__ out) {
    __shared__ int rp[RPW];
    int t = threadIdx.x, b = blockIdx.x;

    if (t < RPW) rp[t] = rptab[b * RPW + t];
    __syncthreads();

    const unsigned* pk = (const unsigned*)((const char*)pkd + (size_t)b * CAPB);
    int node = t >> 2, q = t & 3;
    int n = (b << 7) + node;
    int beg = rp[node], end = rp[node + 1];
    int deg = end - beg;
    const float C = 1.0f / 32767.0f;

    float acc[4] = {0.0f, 0.0f, 0.0f, 0.0f};
    int j = beg;
    for (; j + 3 < end; j += 4) {
        unsigned p0 = NTL(pk + j), p1 = NTL(pk + j + 1);
        unsigned p2 = NTL(pk + j + 2), p3 = NTL(pk + j + 3);
        uint4 w0 = YPH2[(size_t)(p0 & 0x1FFFFu) * 4 + q];
        uint4 w1 = YPH2[(size_t)(p1 & 0x1FFFFu) * 4 + q];
        uint4 w2 = YPH2[(size_t)(p2 & 0x1FFFFu) * 4 + q];
        uint4 w3 = YPH2[(size_t)(p3 & 0x1FFFFu) * 4 + q];
        accq(acc, w0, (float)(p0 >> 17) * C);
        accq(acc, w1, (float)(p1 >> 17) * C);
        accq(acc, w2, (float)(p2 >> 17) * C);
        accq(acc, w3, (float)(p3 >> 17) * C);
    }
    for (; j < end; ++j) {
        unsigned p = NTL(pk + j);
        uint4 w = YPH2[(size_t)(p & 0x1FFFFu) * 4 + q];
        accq(acc, w, (float)(p >> 17) * C);
    }

    if (n < N_NODES) {
        float inv = 1.0f / (deg > 0 ? (float)deg : 1.0f);
        float4 rr = ((const float4*)R2)[(size_t)n * 4 + q];
        float v0 = fmaf(acc[0], inv, rr.x);
        float v1 = fmaf(acc[1], inv, rr.y);
        float v2 = fmaf(acc[2], inv, rr.z);
        float v3 = fmaf(acc[3], inv, rr.w);
        float m = fmaxf(fmaxf(v0, v1), fmaxf(v2, v3));
        m = fmaxf(m, __shfl_xor(m, 1));
        m = fmaxf(m, __shfl_xor(m, 2));
        float s = expf(v0 - m) + expf(v1 - m) + expf(v2 - m) + expf(v3 - m);
        s += __shfl_xor(s, 1);
        s += __shfl_xor(s, 2);
        float lse = m + logf(s);
        float4 ov = make_float4(v0 - lse, v1 - lse, v2 - lse, v3 - lse);
        ((float4*)out)[(size_t)n * 4 + q] = ov;
    }
}

// ---------------------------------------------------------------------------
extern "C" void kernel_launch(void* const* d_in, const int* in_sizes, int n_in,
                              void* d_out, int out_size, void* d_ws, size_t ws_size,
                              hipStream_t stream) {
    const float* x         = (const float*)d_in[0];
    const float* edge_attr = (const float*)d_in[1];
    const int*   edge_idx  = (const int*)d_in[2];
    const float* W1        = (const float*)d_in[3];
    const float* root1     = (const float*)d_in[4];
    const float* b1        = (const float*)d_in[5];
    const float* W2        = (const float*)d_in[6];
    const float* root2     = (const float*)d_in[7];
    const float* b2        = (const float*)d_in[8];
    float* out = (float*)d_out;

    const int* src = edge_idx;
    const int* dst = edge_idx + N_EDGES;

    // workspace layout (byte offsets, 16B aligned), total ~42.0 MB
    char* ws = (char*)d_ws;
    unsigned long long* pkd = (unsigned long long*)(ws); // 782*2560*8 = 16,015,360
    unsigned* YPH1 = (unsigned*)(ws + 16015360);         //  6,400,000
    float*    R1   = (float*)(ws + 22415360);            //  6,400,000
    unsigned* YPH2 = (unsigned*)(ws + 28815360);         //  6,400,000
    float*    R2   = (float*)(ws + 35215360);            //  6,400,000
    int*      cursor = (int*)(ws + 41615360);            //      3,128
    int*      rptab  = (int*)(ws + 41618496);            //    403,512

    hipMemsetAsync(cursor, 0, NBUK * sizeof(int), stream);

    fused_transform_scatter<<<dim3(NCHUNK + NTBLK), 1024, SM_TOTAL, stream>>>(
        x, W1, root1, b1, YPH1, R1, src, dst, edge_attr, cursor, pkd);

    aggregate1<<<dim3(NBUK), 512, 0, stream>>>(
        cursor, pkd, rptab, (const uint4*)YPH1, R1, W2, root2, b2, YPH2, R2);

    aggregate2<<<dim3(NBUK), 512, 0, stream>>>(
        rptab, pkd, (const uint4*)YPH2, R2, out);
}